// Round 1
// baseline (907.344 us; speedup 1.0000x reference)
//
#include <hip/hip_runtime.h>
#include <hip/hip_bf16.h>
#include <stdint.h>

#define NE 8
#define NTOK 8192        // B*T
#define HD 1024
#define FD 4096
#define NSLOT (NTOK * 2)

typedef __attribute__((ext_vector_type(4))) float floatx4;
typedef __attribute__((ext_vector_type(8))) __bf16 bf16x8;

__device__ __forceinline__ unsigned short f2bf(float f) {
    union { float f; unsigned u; } v; v.f = f;
    unsigned r = v.u + 0x7FFFu + ((v.u >> 16) & 1u);   // RNE
    return (unsigned short)(r >> 16);
}

__device__ __forceinline__ void gload_lds16(const unsigned short* g, unsigned short* l) {
    __builtin_amdgcn_global_load_lds(
        (const __attribute__((address_space(1))) void*)g,
        (__attribute__((address_space(3))) void*)l,
        16, 0, 0);
}

// ---------------- cast x fp32 -> bf16 ----------------
__global__ void cast_x_kernel(const float* __restrict__ x, unsigned short* __restrict__ xb, int n4) {
    int i = blockIdx.x * blockDim.x + threadIdx.x;
    if (i < n4) {
        float4 v = ((const float4*)x)[i];
        ushort4 o;
        o.x = f2bf(v.x); o.y = f2bf(v.y); o.z = f2bf(v.z); o.w = f2bf(v.w);
        ((ushort4*)xb)[i] = o;
    }
}

// ------------- transpose + cast: w[e][r][c] (fp32) -> wt[e][c][r] (bf16) -------------
__global__ void transpose_cast_kernel(const float* __restrict__ w, unsigned short* __restrict__ wt,
                                      int rows, int cols) {
    __shared__ unsigned short tile[32][33];
    int e = blockIdx.z;
    int r0 = blockIdx.y * 32;
    int c0 = blockIdx.x * 32;
    const float* ws = w + (size_t)e * rows * cols;
    unsigned short* wd = wt + (size_t)e * rows * cols;
    int tx = threadIdx.x;   // 0..31
    int ty = threadIdx.y;   // 0..7
#pragma unroll
    for (int i = 0; i < 4; i++) {
        int r = ty + 8 * i;
        tile[r][tx] = f2bf(ws[(size_t)(r0 + r) * cols + c0 + tx]);
    }
    __syncthreads();
#pragma unroll
    for (int i = 0; i < 4; i++) {
        int c = ty + 8 * i;
        wd[(size_t)(c0 + c) * rows + r0 + tx] = tile[tx][c];
    }
}

// ---------------- router: logits, top-2 softmax, build per-expert slot lists ----------------
__global__ void router_kernel(const float* __restrict__ x, const float* __restrict__ gw,
                              float* __restrict__ logits, int* __restrict__ counts,
                              int* __restrict__ perm, float* __restrict__ wts) {
    int lane = threadIdx.x & 63;
    int t = blockIdx.x * 4 + (threadIdx.x >> 6);   // one wave per token
    const float* xr = x + (size_t)t * HD;
    float a0=0,a1=0,a2=0,a3=0,a4=0,a5=0,a6=0,a7=0;
    for (int c = lane; c < HD; c += 64) {
        float xv = xr[c];
        const float4* g = (const float4*)(gw + (size_t)c * NE);
        float4 g0 = g[0], g1 = g[1];
        a0 += xv * g0.x; a1 += xv * g0.y; a2 += xv * g0.z; a3 += xv * g0.w;
        a4 += xv * g1.x; a5 += xv * g1.y; a6 += xv * g1.z; a7 += xv * g1.w;
    }
#pragma unroll
    for (int off = 32; off > 0; off >>= 1) {
        a0 += __shfl_xor(a0, off); a1 += __shfl_xor(a1, off);
        a2 += __shfl_xor(a2, off); a3 += __shfl_xor(a3, off);
        a4 += __shfl_xor(a4, off); a5 += __shfl_xor(a5, off);
        a6 += __shfl_xor(a6, off); a7 += __shfl_xor(a7, off);
    }
    if (lane == 0) {
        float l[8] = {a0,a1,a2,a3,a4,a5,a6,a7};
        float4 s0 = make_float4(a0,a1,a2,a3);
        float4 s1 = make_float4(a4,a5,a6,a7);
        ((float4*)(logits + (size_t)t * NE))[0] = s0;
        ((float4*)(logits + (size_t)t * NE))[1] = s1;
        int e0 = 0; float v0 = l[0];
#pragma unroll
        for (int e = 1; e < 8; e++) if (l[e] > v0) { v0 = l[e]; e0 = e; }
        int e1 = -1; float v1 = -3.4e38f;
#pragma unroll
        for (int e = 0; e < 8; e++) if (e != e0 && l[e] > v1) { v1 = l[e]; e1 = e; }
        float ex = __expf(v1 - v0);
        float dn = 1.f + ex;
        wts[2*t]   = 1.f / dn;
        wts[2*t+1] = ex / dn;
        int p0 = atomicAdd(&counts[e0], 1);
        perm[e0 * NTOK + p0] = 2 * t;
        int p1 = atomicAdd(&counts[e1], 1);
        perm[e1 * NTOK + p1] = 2 * t + 1;
    }
}

// ---------------- gathered GEMM, m97 structure ----------------
// C[M x NTOT] = gather(A)[M x KTOT] * Bt[e]^T, Bt stored [NTOT x KTOT] (B^T).
// G1: A row = xb[slot>>1], epilogue relu->bf16 into h[slot].
// !G1: A row = h[slot], epilogue atomicAdd(out[slot>>1], w[slot]*acc).
template<int KTOT, int NTOT, bool G1>
__global__ __launch_bounds__(256, 2)
void moe_gemm(const unsigned short* __restrict__ A,
              const unsigned short* __restrict__ Bt,
              unsigned short* __restrict__ Hout,
              float* __restrict__ Out,
              const int* __restrict__ counts,
              const int* __restrict__ perm,
              const float* __restrict__ wts) {
    int e = blockIdx.y >> 6;
    int mtile = blockIdx.y & 63;
    int cnt = counts[e];
    if (mtile * 128 >= cnt) return;
    int n0 = blockIdx.x * 128;

    __shared__ unsigned short lds[2 * 128 * 64];   // A tile then B tile, 32 KiB
    __shared__ int slotLds[128];
    __shared__ float wLds[128];

    int tid = threadIdx.x;
    int lane = tid & 63;
    int wv = tid >> 6;
    const int* permE = perm + e * NTOK + mtile * 128;

    if (tid < 128) {
        int s = (mtile * 128 + tid < cnt) ? permE[tid] : -1;
        slotLds[tid] = s;
        if (!G1) wLds[tid] = (s >= 0) ? wts[s] : 0.f;
    }

    // staging row pointers: thread handles rows r_it = it*32 + (tid>>3)
    const unsigned short* aRow[4];
    const unsigned short* bRow[4];
#pragma unroll
    for (int it = 0; it < 4; it++) {
        int r = it * 32 + (tid >> 3);
        int s = (mtile * 128 + r < cnt) ? permE[r] : permE[0];   // clamp to a valid row
        size_t arow = G1 ? (size_t)(s >> 1) : (size_t)s;
        aRow[it] = A + arow * KTOT;
        bRow[it] = Bt + ((size_t)e * NTOT + n0 + r) * KTOT;
    }
    // XOR swizzle: logical k-chunk j of row r lives at physical chunk j^(r&7).
    // Staging lane (row r, phys chunk kc=tid&7) fetches global chunk kc^(r&7).
    int koff = ((tid & 7) ^ ((tid >> 3) & 7)) * 8;   // elements
    unsigned short* ldsA = lds;
    unsigned short* ldsB = lds + 128 * 64;
    int wbase = (tid & 192) * 8;                     // wave-uniform LDS chunk base (elems)

    floatx4 acc[4][4];
    floatx4 zero = {0.f, 0.f, 0.f, 0.f};
#pragma unroll
    for (int i = 0; i < 4; i++)
#pragma unroll
        for (int j = 0; j < 4; j++) acc[i][j] = zero;

    int m = lane & 15, quad = lane >> 4;
    int rA = (wv >> 1) * 64 + m;     // + mi*16
    int rB = (wv & 1) * 64 + m;      // + ni*16
    int xs = m & 7;                  // fragment-read swizzle (row&7 == m&7)

    for (int k0 = 0; k0 < KTOT; k0 += 64) {
#pragma unroll
        for (int it = 0; it < 4; it++)
            gload_lds16(aRow[it] + k0 + koff, ldsA + it * 2048 + wbase);
#pragma unroll
        for (int it = 0; it < 4; it++)
            gload_lds16(bRow[it] + k0 + koff, ldsB + it * 2048 + wbase);
        __builtin_amdgcn_s_waitcnt(0);
        __syncthreads();
#pragma unroll
        for (int kk = 0; kk < 2; kk++) {
            bf16x8 af[4], bfr[4];
#pragma unroll
            for (int mi = 0; mi < 4; mi++)
                af[mi] = *(const bf16x8*)(ldsA + (((rA + mi * 16) * 8 + ((kk * 4 + quad) ^ xs)) * 8));
#pragma unroll
            for (int ni = 0; ni < 4; ni++)
                bfr[ni] = *(const bf16x8*)(ldsB + (((rB + ni * 16) * 8 + ((kk * 4 + quad) ^ xs)) * 8));
#pragma unroll
            for (int mi = 0; mi < 4; mi++)
#pragma unroll
                for (int ni = 0; ni < 4; ni++)
                    acc[mi][ni] = __builtin_amdgcn_mfma_f32_16x16x32_bf16(af[mi], bfr[ni], acc[mi][ni], 0, 0, 0);
        }
        __syncthreads();
    }

    // epilogue: C/D layout col = lane&15, row = quad*4 + reg
    int colb = (wv & 1) * 64 + m;          // + ni*16
    int rb = (wv >> 1) * 64 + quad * 4;    // + mi*16 + reg
#pragma unroll
    for (int mi = 0; mi < 4; mi++) {
#pragma unroll
        for (int reg = 0; reg < 4; reg++) {
            int rl = rb + mi * 16 + reg;
            int s = slotLds[rl];
            if (s < 0) continue;
            if (G1) {
                unsigned short* hr = Hout + (size_t)s * NTOT + n0 + colb;
#pragma unroll
                for (int ni = 0; ni < 4; ni++) {
                    float v = acc[mi][ni][reg];
                    hr[ni * 16] = f2bf(v > 0.f ? v : 0.f);
                }
            } else {
                float w = wLds[rl];
                float* orow = Out + (size_t)(s >> 1) * NTOT + n0 + colb;
#pragma unroll
                for (int ni = 0; ni < 4; ni++)
                    atomicAdd(&orow[ni * 16], w * acc[mi][ni][reg]);
            }
        }
    }
}

extern "C" void kernel_launch(void* const* d_in, const int* in_sizes, int n_in,
                              void* d_out, int out_size, void* d_ws, size_t ws_size,
                              hipStream_t stream) {
    (void)in_sizes; (void)n_in; (void)out_size;
    const float* x  = (const float*)d_in[0];
    const float* gw = (const float*)d_in[1];
    const float* w1 = (const float*)d_in[2];
    const float* w2 = (const float*)d_in[3];
    float* out = (float*)d_out;
    float* logits = out + (size_t)NTOK * HD;

    char* ws = (char*)d_ws;
    int*   counts = (int*)ws;                              // 32 B
    int*   perm   = (int*)(ws + 256);                      // 8*8192*4 = 256 KiB
    float* wts    = (float*)(ws + 256 + 262144);           // 64 KiB
    unsigned short* xb    = (unsigned short*)(ws + 393216);            // 16 MiB
    unsigned short* wtbuf = xb + (size_t)NTOK * HD;                    // 64 MiB (w1t, then w2t)
    unsigned short* h     = wtbuf + (size_t)NE * HD * FD;              // 128 MiB
    size_t needed = 393216 + (size_t)NTOK*HD*2 + (size_t)NE*HD*FD*2 + (size_t)NSLOT*FD*2;
    if (ws_size < needed) return;   // workspace too small — cannot run

    hipMemsetAsync(counts, 0, 32, stream);
    hipMemsetAsync(out, 0, (size_t)NTOK * HD * sizeof(float), stream);

    cast_x_kernel<<<(NTOK * HD / 4 + 255) / 256, 256, 0, stream>>>(x, xb, NTOK * HD / 4);
    // w1: [E][H][F] -> w1t [E][F][H]
    transpose_cast_kernel<<<dim3(FD / 32, HD / 32, NE), dim3(32, 8), 0, stream>>>(w1, wtbuf, HD, FD);
    router_kernel<<<NTOK / 4, 256, 0, stream>>>(x, gw, logits, counts, perm, wts);
    // h[s] = relu(xb[token] @ w1[e]) : K=1024, N=4096
    moe_gemm<HD, FD, true><<<dim3(FD / 128, NE * 64), 256, 0, stream>>>(
        xb, wtbuf, h, nullptr, counts, perm, wts);
    // w2: [E][F][H] -> w2t [E][H][F] (reuse wtbuf; stream order serializes after gemm1)
    transpose_cast_kernel<<<dim3(HD / 32, FD / 32, NE), dim3(32, 8), 0, stream>>>(w2, wtbuf, FD, HD);
    // out[t] += w[s] * (h[s] @ w2[e]) : K=4096, N=1024
    moe_gemm<FD, HD, false><<<dim3(HD / 128, NE * 64), 256, 0, stream>>>(
        h, wtbuf, nullptr, out, counts, perm, wts);
}